// Round 1
// baseline (1690.855 us; speedup 1.0000x reference)
//
#include <hip/hip_runtime.h>
#include <math.h>

#define B 64
#define T 4096
#define D 256
#define U 256
#define TB 32            // tokens per block in scores kernel
#define TCH 256          // tokens per chunk in context kernel
#define NCH (T / TCH)    // 16 chunks

// ---------------- kernel 0: W = W1 + W2 (tanh(q+k) = tanh(A@(W1+W2))) ---------
__global__ void wsum_kernel(const float* __restrict__ W1, const float* __restrict__ W2,
                            float* __restrict__ W) {
    int i = blockIdx.x * 256 + threadIdx.x;
    W[i] = W1[i] + W2[i];
}

// ---------------- kernel 1: scores s[b,t] = sum_u tanh((A@W)[u]) * v[u] -------
// Block = 256 threads (thread u owns column u of W), TB tokens per block.
// A-row loads are block-uniform -> scalar loads; W column chunk in VGPRs;
// inner loop is pure v_fmac_f32.
__global__ __launch_bounds__(256, 4) void scores_kernel(
    const float* __restrict__ A,   // [B*T, D]
    const float* __restrict__ W,   // [D, U]
    const float* __restrict__ v,   // [U]
    float* __restrict__ s_out)     // [B*T] (d_out attn region, pre-softmax)
{
    const int u = threadIdx.x;                 // 0..255
    const long tok0 = (long)blockIdx.x * TB;

    float h[TB];
#pragma unroll
    for (int t = 0; t < TB; ++t) h[t] = 0.f;

    const float* Abase = A + tok0 * D;
    for (int kc = 0; kc < D; kc += 8) {
        const float w0 = W[(kc + 0) * U + u];
        const float w1 = W[(kc + 1) * U + u];
        const float w2 = W[(kc + 2) * U + u];
        const float w3 = W[(kc + 3) * U + u];
        const float w4 = W[(kc + 4) * U + u];
        const float w5 = W[(kc + 5) * U + u];
        const float w6 = W[(kc + 6) * U + u];
        const float w7 = W[(kc + 7) * U + u];
#pragma unroll
        for (int t = 0; t < TB; ++t) {
            const float4* ap = (const float4*)(Abase + (long)t * D + kc);
            const float4 a0 = ap[0];
            const float4 a1 = ap[1];
            float hv = h[t];
            hv = fmaf(a0.x, w0, hv);
            hv = fmaf(a0.y, w1, hv);
            hv = fmaf(a0.z, w2, hv);
            hv = fmaf(a0.w, w3, hv);
            hv = fmaf(a1.x, w4, hv);
            hv = fmaf(a1.y, w5, hv);
            hv = fmaf(a1.z, w6, hv);
            hv = fmaf(a1.w, w7, hv);
            h[t] = hv;
        }
    }

    const float vu = v[u];
    __shared__ float red[4][TB];
    const int wave = threadIdx.x >> 6;
    const int lane = threadIdx.x & 63;
#pragma unroll
    for (int t = 0; t < TB; ++t) {
        float p = tanhf(h[t]) * vu;
        for (int off = 32; off > 0; off >>= 1)
            p += __shfl_down(p, off);
        if (lane == 0) red[wave][t] = p;
    }
    __syncthreads();
    if (threadIdx.x < TB) {
        const int t = threadIdx.x;
        s_out[tok0 + t] = red[0][t] + red[1][t] + red[2][t] + red[3][t];
    }
}

// ---------------- kernel 2: softmax over T, in place ---------------------------
__global__ __launch_bounds__(1024) void softmax_kernel(float* __restrict__ attn) {
    const int b = blockIdx.x;
    float* row = attn + (long)b * T;
    const int tid = threadIdx.x;          // 0..1023, each owns 4 elements
    const int wave = tid >> 6, lane = tid & 63;

    __shared__ float lmax[16];
    __shared__ float lsum[16];
    __shared__ float bcast[2];

    float4 s = ((const float4*)row)[tid];
    float m = fmaxf(fmaxf(s.x, s.y), fmaxf(s.z, s.w));
    for (int off = 32; off > 0; off >>= 1) m = fmaxf(m, __shfl_down(m, off));
    if (lane == 0) lmax[wave] = m;
    __syncthreads();
    if (tid == 0) {
        float mm = lmax[0];
        for (int i = 1; i < 16; ++i) mm = fmaxf(mm, lmax[i]);
        bcast[0] = mm;
    }
    __syncthreads();
    m = bcast[0];

    float4 e;
    e.x = expf(s.x - m); e.y = expf(s.y - m);
    e.z = expf(s.z - m); e.w = expf(s.w - m);
    float sum = e.x + e.y + e.z + e.w;
    for (int off = 32; off > 0; off >>= 1) sum += __shfl_down(sum, off);
    if (lane == 0) lsum[wave] = sum;
    __syncthreads();
    if (tid == 0) {
        float ss = 0.f;
        for (int i = 0; i < 16; ++i) ss += lsum[i];
        bcast[1] = 1.0f / ss;
    }
    __syncthreads();
    const float inv = bcast[1];
    e.x *= inv; e.y *= inv; e.z *= inv; e.w *= inv;
    ((float4*)row)[tid] = e;
}

// ---------------- kernel 3: context partials ----------------------------------
// Block = (chunk, b); 4 token-groups x 64 lanes (float4 over D).
__global__ __launch_bounds__(256) void context_partial_kernel(
    const float* __restrict__ A, const float* __restrict__ attn,
    float* __restrict__ part)   // [NCH][B][D]
{
    const int chunk = blockIdx.x;
    const int b = blockIdx.y;
    const int tg = threadIdx.x >> 6;          // 0..3
    const int l = threadIdx.x & 63;
    const int dl = l * 4;
    const long tokbase = (long)b * T + (long)chunk * TCH;

    float4 acc = make_float4(0.f, 0.f, 0.f, 0.f);
    for (int t = tg; t < TCH; t += 4) {
        const long tok = tokbase + t;
        const float a = attn[tok];
        const float4 x = *(const float4*)(A + tok * D + dl);
        acc.x = fmaf(a, x.x, acc.x);
        acc.y = fmaf(a, x.y, acc.y);
        acc.z = fmaf(a, x.z, acc.z);
        acc.w = fmaf(a, x.w, acc.w);
    }

    __shared__ float4 red[4][64];
    red[tg][l] = acc;
    __syncthreads();
    if (tg == 0) {
        float4 r = red[0][l];
        const float4 r1 = red[1][l], r2 = red[2][l], r3 = red[3][l];
        r.x += r1.x + r2.x + r3.x;
        r.y += r1.y + r2.y + r3.y;
        r.z += r1.z + r2.z + r3.z;
        r.w += r1.w + r2.w + r3.w;
        float* p = part + ((long)chunk * B + b) * D + dl;
        p[0] = r.x; p[1] = r.y; p[2] = r.z; p[3] = r.w;
    }
}

// ---------------- kernel 4: reduce partials -> context ------------------------
__global__ void context_reduce_kernel(const float* __restrict__ part,
                                      float* __restrict__ ctx) {
    const int i = blockIdx.x * 256 + threadIdx.x;  // 0..B*D-1
    float s = 0.f;
    for (int c = 0; c < NCH; ++c) s += part[(long)c * (B * D) + i];
    ctx[i] = s;
}

extern "C" void kernel_launch(void* const* d_in, const int* in_sizes, int n_in,
                              void* d_out, int out_size, void* d_ws, size_t ws_size,
                              hipStream_t stream) {
    const float* lstm = (const float*)d_in[0];  // [B,T,D]
    const float* W1   = (const float*)d_in[1];  // [D,U]
    const float* W2   = (const float*)d_in[2];  // [D,U]
    const float* v    = (const float*)d_in[3];  // [U,1]

    float* out  = (float*)d_out;
    float* ctx  = out;            // [B*D] = 16384 floats
    float* attn = out + B * D;    // [B*T] = 262144 floats

    float* W    = (float*)d_ws;           // 65536 floats (256 KB)
    float* part = W + D * U;              // NCH*B*D = 262144 floats (1 MB)

    wsum_kernel<<<(D * U) / 256, 256, 0, stream>>>(W1, W2, W);
    scores_kernel<<<(B * T) / TB, 256, 0, stream>>>(lstm, W, v, attn);
    softmax_kernel<<<B, 1024, 0, stream>>>(attn);
    context_partial_kernel<<<dim3(NCH, B), 256, 0, stream>>>(lstm, attn, part);
    context_reduce_kernel<<<(B * D) / 256, 256, 0, stream>>>(part, ctx);
}

// Round 2
// 484.596 us; speedup vs baseline: 3.4892x; 3.4892x over previous
//
#include <hip/hip_runtime.h>
#include <math.h>

#define B 64
#define T 4096
#define D 256
#define U 256

typedef __attribute__((ext_vector_type(8)))  short s16x8;
typedef __attribute__((ext_vector_type(16))) float f32x16;

#define MT 32                 // rows per m-step
#define SPB 32                // m-steps per block
#define NBLK ((B*T)/(MT*SPB)) // 256 blocks = 1/CU
#define LDAP 33               // padded m-stride (uint4 units) per k8-row

#define TCH 256               // tokens per chunk in context kernel
#define NCH (T / TCH)         // 16 chunks

// ================= scores: s[b,t] = sum_u tanh((A@(W1+W2))[u]) * v[u] ========
// Split-bf16 MFMA: a*w ~= ah*wh + ah*wl + al*wh (truncation splits).
// Wave w owns cols [32w,32w+32); B-frags (W hi/lo) live in VGPRs for the
// whole block; A staged per 32-row step as hi/lo bf16 in LDS.
__global__ __launch_bounds__(512, 2) void scores_mfma_kernel(
    const float* __restrict__ A,    // [B*T, D]
    const float* __restrict__ W1,   // [D, U]
    const float* __restrict__ W2,   // [D, U]
    const float* __restrict__ v,    // [U]
    float* __restrict__ s_out)      // [B*T] pre-softmax scores
{
  __shared__ uint4 AH[32 * LDAP];   // [k8][m] 8 bf16 hi per cell
  __shared__ uint4 AL[32 * LDAP];   // lo
  __shared__ float red[32][8];      // [row][wave] score partials

  const int tid  = threadIdx.x;
  const int lane = tid & 63;
  const int wv   = tid >> 6;        // 0..7
  const int l31  = lane & 31;
  const int half = lane >> 5;

  // ---- build register-resident B-fragments from W1+W2 (once per block) ----
  // frag layout (32x32x16 bf16 B-operand): elem j <-> W[k = 16s + 8*half + j][n]
  const int n = wv * 32 + l31;
  s16x8 Bh[16], Bl[16];
#pragma unroll
  for (int s = 0; s < 16; ++s) {
    s16x8 bh, bl;
#pragma unroll
    for (int j = 0; j < 8; ++j) {
      const int k = s * 16 + half * 8 + j;
      const float w = W1[k * 256 + n] + W2[k * 256 + n];
      const unsigned int uw = __float_as_uint(w);
      const float wl = w - __uint_as_float(uw & 0xffff0000u);
      bh[j] = (short)(uw >> 16);
      bl[j] = (short)(__float_as_uint(wl) >> 16);
    }
    Bh[s] = bh; Bl[s] = bl;
  }
  const float vv = v[n];

  // staging map: thread -> (row sm, float4-chunk sc0 + 16*i)
  const int sm  = tid >> 4;   // 0..31
  const int sc0 = tid & 15;

  const size_t row0 = (size_t)blockIdx.x * (MT * SPB);
  float4 rg[4];
  {
    const float4* src = (const float4*)(A + (row0 + sm) * 256);
#pragma unroll
    for (int i = 0; i < 4; ++i) rg[i] = src[sc0 + 16 * i];
  }

  for (int step = 0; step < SPB; ++step) {
    const size_t rowbase = row0 + (size_t)step * MT;

    // ---- convert prefetched tile to hi/lo bf16, write LDS ----
#pragma unroll
    for (int i = 0; i < 4; ++i) {
      const float4 a = rg[i];
      const int k  = 4 * (sc0 + 16 * i);
      const int k8 = k >> 3;
      const int off = (k >> 2) & 1;
      const unsigned int ux = __float_as_uint(a.x), uy = __float_as_uint(a.y);
      const unsigned int uz = __float_as_uint(a.z), uw = __float_as_uint(a.w);
      const uint2 hi2 = make_uint2((ux >> 16) | (uy & 0xffff0000u),
                                   (uz >> 16) | (uw & 0xffff0000u));
      const float lx = a.x - __uint_as_float(ux & 0xffff0000u);
      const float ly = a.y - __uint_as_float(uy & 0xffff0000u);
      const float lz = a.z - __uint_as_float(uz & 0xffff0000u);
      const float lw = a.w - __uint_as_float(uw & 0xffff0000u);
      const uint2 lo2 = make_uint2(
          (__float_as_uint(lx) >> 16) | (__float_as_uint(ly) & 0xffff0000u),
          (__float_as_uint(lz) >> 16) | (__float_as_uint(lw) & 0xffff0000u));
      ((uint2*)&AH[k8 * LDAP + sm])[off] = hi2;
      ((uint2*)&AL[k8 * LDAP + sm])[off] = lo2;
    }
    __syncthreads();

    // prefetch next tile (latency hidden under MFMA phase)
    if (step + 1 < SPB) {
      const float4* src = (const float4*)(A + (rowbase + MT + sm) * 256);
#pragma unroll
      for (int i = 0; i < 4; ++i) rg[i] = src[sc0 + 16 * i];
    }

    // ---- MFMA: 3-product split-bf16, 3 independent acc chains ----
    f32x16 a0 = {}, a1 = {}, a2 = {};
#pragma unroll
    for (int s = 0; s < 16; ++s) {
      const uint4 qh = AH[(2 * s + half) * LDAP + l31];
      const uint4 ql = AL[(2 * s + half) * LDAP + l31];
      const s16x8 ah = __builtin_bit_cast(s16x8, qh);
      const s16x8 al = __builtin_bit_cast(s16x8, ql);
      a0 = __builtin_amdgcn_mfma_f32_32x32x16_bf16(ah, Bh[s], a0, 0, 0, 0);
      a1 = __builtin_amdgcn_mfma_f32_32x32x16_bf16(ah, Bl[s], a1, 0, 0, 0);
      a2 = __builtin_amdgcn_mfma_f32_32x32x16_bf16(al, Bh[s], a2, 0, 0, 0);
    }

    // ---- epilogue: tanh, *v[u], reduce over this wave's 32 cols ----
#pragma unroll
    for (int r = 0; r < 16; ++r) {
      const float x = a0[r] + a1[r] + a2[r];
      const float e = __expf(x + x);                     // e^{2x}
      const float t = 1.f - 2.f * __builtin_amdgcn_rcpf(e + 1.f);  // tanh
      float p = t * vv;
      p += __shfl_xor(p, 1);
      p += __shfl_xor(p, 2);
      p += __shfl_xor(p, 4);
      p += __shfl_xor(p, 8);
      p += __shfl_xor(p, 16);
      if (l31 == 0)
        red[(r & 3) + 8 * (r >> 2) + 4 * half][wv] = p;
    }
    __syncthreads();

    if (tid < 32) {
      const float4* rp = (const float4*)&red[tid][0];
      const float4 ra = rp[0], rb = rp[1];
      s_out[rowbase + tid] = ra.x + ra.y + ra.z + ra.w + rb.x + rb.y + rb.z + rb.w;
    }
    // next iteration's LDS writes are safe: all AH/AL reads completed before
    // the barrier above; red reads (tid<32) complete before those threads
    // reach the next top-of-loop barrier.
  }
}

// ================= softmax over T, in place ==================================
__global__ __launch_bounds__(1024) void softmax_kernel(float* __restrict__ attn) {
    const int b = blockIdx.x;
    float* row = attn + (long)b * T;
    const int tid = threadIdx.x;
    const int wave = tid >> 6, lane = tid & 63;

    __shared__ float lmax[16];
    __shared__ float lsum[16];
    __shared__ float bcast[2];

    float4 s = ((const float4*)row)[tid];
    float m = fmaxf(fmaxf(s.x, s.y), fmaxf(s.z, s.w));
    for (int off = 32; off > 0; off >>= 1) m = fmaxf(m, __shfl_down(m, off));
    if (lane == 0) lmax[wave] = m;
    __syncthreads();
    if (tid == 0) {
        float mm = lmax[0];
        for (int i = 1; i < 16; ++i) mm = fmaxf(mm, lmax[i]);
        bcast[0] = mm;
    }
    __syncthreads();
    m = bcast[0];

    float4 e;
    e.x = expf(s.x - m); e.y = expf(s.y - m);
    e.z = expf(s.z - m); e.w = expf(s.w - m);
    float sum = e.x + e.y + e.z + e.w;
    for (int off = 32; off > 0; off >>= 1) sum += __shfl_down(sum, off);
    if (lane == 0) lsum[wave] = sum;
    __syncthreads();
    if (tid == 0) {
        float ss = 0.f;
        for (int i = 0; i < 16; ++i) ss += lsum[i];
        bcast[1] = 1.0f / ss;
    }
    __syncthreads();
    const float inv = bcast[1];
    e.x *= inv; e.y *= inv; e.z *= inv; e.w *= inv;
    ((float4*)row)[tid] = e;
}

// ================= context partials =========================================
__global__ __launch_bounds__(256) void context_partial_kernel(
    const float* __restrict__ A, const float* __restrict__ attn,
    float* __restrict__ part)   // [NCH][B][D]
{
    const int chunk = blockIdx.x;
    const int b = blockIdx.y;
    const int tg = threadIdx.x >> 6;          // 0..3
    const int l = threadIdx.x & 63;
    const int dl = l * 4;
    const long tokbase = (long)b * T + (long)chunk * TCH;

    float4 acc = make_float4(0.f, 0.f, 0.f, 0.f);
    for (int t = tg; t < TCH; t += 4) {
        const long tok = tokbase + t;
        const float a = attn[tok];
        const float4 x = *(const float4*)(A + tok * D + dl);
        acc.x = fmaf(a, x.x, acc.x);
        acc.y = fmaf(a, x.y, acc.y);
        acc.z = fmaf(a, x.z, acc.z);
        acc.w = fmaf(a, x.w, acc.w);
    }

    __shared__ float4 red[4][64];
    red[tg][l] = acc;
    __syncthreads();
    if (tg == 0) {
        float4 r = red[0][l];
        const float4 r1 = red[1][l], r2 = red[2][l], r3 = red[3][l];
        r.x += r1.x + r2.x + r3.x;
        r.y += r1.y + r2.y + r3.y;
        r.z += r1.z + r2.z + r3.z;
        r.w += r1.w + r2.w + r3.w;
        float* p = part + ((long)chunk * B + b) * D + dl;
        p[0] = r.x; p[1] = r.y; p[2] = r.z; p[3] = r.w;
    }
}

// ================= reduce partials -> context ================================
__global__ void context_reduce_kernel(const float* __restrict__ part,
                                      float* __restrict__ ctx) {
    const int i = blockIdx.x * 256 + threadIdx.x;
    float s = 0.f;
    for (int c = 0; c < NCH; ++c) s += part[(long)c * (B * D) + i];
    ctx[i] = s;
}

extern "C" void kernel_launch(void* const* d_in, const int* in_sizes, int n_in,
                              void* d_out, int out_size, void* d_ws, size_t ws_size,
                              hipStream_t stream) {
    const float* lstm = (const float*)d_in[0];  // [B,T,D]
    const float* W1   = (const float*)d_in[1];  // [D,U]
    const float* W2   = (const float*)d_in[2];  // [D,U]
    const float* v    = (const float*)d_in[3];  // [U,1]

    float* out  = (float*)d_out;
    float* ctx  = out;            // [B*D]
    float* attn = out + B * D;    // [B*T]

    float* part = (float*)d_ws;   // NCH*B*D floats

    scores_mfma_kernel<<<NBLK, 512, 0, stream>>>(lstm, W1, W2, v, attn);
    softmax_kernel<<<B, 1024, 0, stream>>>(attn);
    context_partial_kernel<<<dim3(NCH, B), 256, 0, stream>>>(lstm, attn, part);
    context_reduce_kernel<<<(B * D) / 256, 256, 0, stream>>>(part, ctx);
}

// Round 3
// 443.935 us; speedup vs baseline: 3.8088x; 1.0916x over previous
//
#include <hip/hip_runtime.h>
#include <math.h>

#define B 64
#define T 4096
#define D 256
#define U 256

typedef __attribute__((ext_vector_type(8)))  short s16x8;
typedef __attribute__((ext_vector_type(16))) float f32x16;

#define MT 32                 // rows per m-step
#define SPB 16                // m-steps per block
#define NBLK ((B*T)/(MT*SPB)) // 512 blocks = 2/CU
#define LDAP 33               // padded m-stride (uint4 units) per k8-row

#define TCH 128               // tokens per chunk in context kernel
#define NCH (T / TCH)         // 32 chunks

// DPP cross-lane add (VALU pipe, not LDS): v += lane-permuted v
#define DPP_ADD(v, ctrl)                                                     \
  v += __int_as_float(__builtin_amdgcn_update_dpp(                           \
      0, __float_as_int(v), ctrl, 0xF, 0xF, true))

// ================= scores: s[b,t] = sum_u tanh((A@(W1+W2))[u]) * v[u] ========
// Split-bf16 MFMA: a*w ~= ah*wh + ah*wl + al*wh (truncation splits).
// Wave w owns cols [32w,32w+32); B-frags (W hi/lo) live in VGPRs for the
// whole block; A staged per 32-row step as hi/lo bf16 in LDS.
__global__ __launch_bounds__(512, 2) void scores_mfma_kernel(
    const float* __restrict__ A,    // [B*T, D]
    const float* __restrict__ W1,   // [D, U]
    const float* __restrict__ W2,   // [D, U]
    const float* __restrict__ v,    // [U]
    float* __restrict__ s_out)      // [B*T] pre-softmax scores
{
  __shared__ uint4 AH[32 * LDAP];   // [k8][m] 8 bf16 hi per cell
  __shared__ uint4 AL[32 * LDAP];   // lo
  __shared__ float red[32][8];      // [row][wave] score partials

  const int tid  = threadIdx.x;
  const int lane = tid & 63;
  const int wv   = tid >> 6;        // 0..7
  const int l31  = lane & 31;
  const int half = lane >> 5;

  // ---- build register-resident B-fragments from W1+W2 (once per block) ----
  // frag layout (32x32x16 bf16 B-operand): elem j <-> W[k = 16s + 8*half + j][n]
  const int n = wv * 32 + l31;
  s16x8 Bh[16], Bl[16];
#pragma unroll
  for (int s = 0; s < 16; ++s) {
    s16x8 bh, bl;
#pragma unroll
    for (int j = 0; j < 8; ++j) {
      const int k = s * 16 + half * 8 + j;
      const float w = W1[k * 256 + n] + W2[k * 256 + n];
      const unsigned int uw = __float_as_uint(w);
      const float wl = w - __uint_as_float(uw & 0xffff0000u);
      bh[j] = (short)(uw >> 16);
      bl[j] = (short)(__float_as_uint(wl) >> 16);
    }
    Bh[s] = bh; Bl[s] = bl;
  }
  const float vv = v[n];

  // staging map: thread -> (row sm, float4-chunk sc0 + 16*i)
  const int sm  = tid >> 4;   // 0..31
  const int sc0 = tid & 15;

  const size_t row0 = (size_t)blockIdx.x * (MT * SPB);
  float4 rg[4];
  {
    const float4* src = (const float4*)(A + (row0 + sm) * 256);
#pragma unroll
    for (int i = 0; i < 4; ++i) rg[i] = src[sc0 + 16 * i];
  }

  for (int step = 0; step < SPB; ++step) {
    const size_t rowbase = row0 + (size_t)step * MT;

    // ---- convert prefetched tile to hi/lo bf16, write LDS ----
#pragma unroll
    for (int i = 0; i < 4; ++i) {
      const float4 a = rg[i];
      const int k  = 4 * (sc0 + 16 * i);
      const int k8 = k >> 3;
      const int off = (k >> 2) & 1;
      const unsigned int ux = __float_as_uint(a.x), uy = __float_as_uint(a.y);
      const unsigned int uz = __float_as_uint(a.z), uw = __float_as_uint(a.w);
      const uint2 hi2 = make_uint2((ux >> 16) | (uy & 0xffff0000u),
                                   (uz >> 16) | (uw & 0xffff0000u));
      const float lx = a.x - __uint_as_float(ux & 0xffff0000u);
      const float ly = a.y - __uint_as_float(uy & 0xffff0000u);
      const float lz = a.z - __uint_as_float(uz & 0xffff0000u);
      const float lw = a.w - __uint_as_float(uw & 0xffff0000u);
      const uint2 lo2 = make_uint2(
          (__float_as_uint(lx) >> 16) | (__float_as_uint(ly) & 0xffff0000u),
          (__float_as_uint(lz) >> 16) | (__float_as_uint(lw) & 0xffff0000u));
      ((uint2*)&AH[k8 * LDAP + sm])[off] = hi2;
      ((uint2*)&AL[k8 * LDAP + sm])[off] = lo2;
    }
    __syncthreads();

    // prefetch next tile (latency hidden under MFMA phase)
    if (step + 1 < SPB) {
      const float4* src = (const float4*)(A + (rowbase + MT + sm) * 256);
#pragma unroll
      for (int i = 0; i < 4; ++i) rg[i] = src[sc0 + 16 * i];
    }

    // ---- MFMA: 3-product split-bf16, 3 independent acc chains ----
    f32x16 a0 = {}, a1 = {}, a2 = {};
#pragma unroll
    for (int s = 0; s < 16; ++s) {
      const uint4 qh = AH[(2 * s + half) * LDAP + l31];
      const uint4 ql = AL[(2 * s + half) * LDAP + l31];
      const s16x8 ah = __builtin_bit_cast(s16x8, qh);
      const s16x8 al = __builtin_bit_cast(s16x8, ql);
      a0 = __builtin_amdgcn_mfma_f32_32x32x16_bf16(ah, Bh[s], a0, 0, 0, 0);
      a1 = __builtin_amdgcn_mfma_f32_32x32x16_bf16(ah, Bl[s], a1, 0, 0, 0);
      a2 = __builtin_amdgcn_mfma_f32_32x32x16_bf16(al, Bh[s], a2, 0, 0, 0);
    }

    // ---- epilogue: tanh, *v[u], reduce wave's 32 cols (DPP = VALU pipe) ----
#pragma unroll
    for (int r = 0; r < 16; ++r) {
      const float x = a0[r] + a1[r] + a2[r];
      const float e = __expf(x + x);                     // e^{2x}
      float p = (1.f - 2.f * __builtin_amdgcn_rcpf(e + 1.f)) * vv;  // tanh*v
      DPP_ADD(p, 0xB1);   // quad_perm {1,0,3,2}: + lane^1
      DPP_ADD(p, 0x4E);   // quad_perm {2,3,0,1}: + lane^2
      DPP_ADD(p, 0x141);  // row_half_mirror: + mirrored-in-8 (has quad-sum)
      DPP_ADD(p, 0x140);  // row_mirror: + mirrored-in-16 (has 8-sum)
      // now every lane in a 16-row has its 16-sum; add the other 16-row:
      p += __int_as_float(
          __builtin_amdgcn_ds_swizzle(__float_as_int(p), 0x401F));  // xor16
      if (l31 == 0)
        red[(r & 3) + 8 * (r >> 2) + 4 * half][wv] = p;
    }
    __syncthreads();

    if (tid < 32) {
      const float4* rp = (const float4*)&red[tid][0];
      const float4 ra = rp[0], rb = rp[1];
      s_out[rowbase + tid] = ra.x + ra.y + ra.z + ra.w + rb.x + rb.y + rb.z + rb.w;
    }
  }
}

// ================= softmax over T, in place ==================================
__global__ __launch_bounds__(1024) void softmax_kernel(float* __restrict__ attn) {
    const int b = blockIdx.x;
    float* row = attn + (long)b * T;
    const int tid = threadIdx.x;
    const int wave = tid >> 6, lane = tid & 63;

    __shared__ float lmax[16];
    __shared__ float lsum[16];
    __shared__ float bcast[2];

    float4 s = ((const float4*)row)[tid];
    float m = fmaxf(fmaxf(s.x, s.y), fmaxf(s.z, s.w));
    for (int off = 32; off > 0; off >>= 1) m = fmaxf(m, __shfl_down(m, off));
    if (lane == 0) lmax[wave] = m;
    __syncthreads();
    if (tid == 0) {
        float mm = lmax[0];
        for (int i = 1; i < 16; ++i) mm = fmaxf(mm, lmax[i]);
        bcast[0] = mm;
    }
    __syncthreads();
    m = bcast[0];

    float4 e;
    e.x = expf(s.x - m); e.y = expf(s.y - m);
    e.z = expf(s.z - m); e.w = expf(s.w - m);
    float sum = e.x + e.y + e.z + e.w;
    for (int off = 32; off > 0; off >>= 1) sum += __shfl_down(sum, off);
    if (lane == 0) lsum[wave] = sum;
    __syncthreads();
    if (tid == 0) {
        float ss = 0.f;
        for (int i = 0; i < 16; ++i) ss += lsum[i];
        bcast[1] = 1.0f / ss;
    }
    __syncthreads();
    const float inv = bcast[1];
    e.x *= inv; e.y *= inv; e.z *= inv; e.w *= inv;
    ((float4*)row)[tid] = e;
}

// ================= context partials =========================================
// Block = (chunk, b): 4 token-groups x 64 lanes; tg owns 32 consecutive tokens,
// attn loaded as float4, A rows as coalesced float4 per lane.
__global__ __launch_bounds__(256, 4) void context_partial_kernel(
    const float* __restrict__ A, const float* __restrict__ attn,
    float* __restrict__ part)   // [NCH][B][D]
{
    const int chunk = blockIdx.x;
    const int b = blockIdx.y;
    const int tg = threadIdx.x >> 6;          // 0..3
    const int l = threadIdx.x & 63;
    const int dl = l * 4;
    const long tokbase = (long)b * T + (long)chunk * TCH + (long)tg * 32;

    const float4* wp = (const float4*)(attn + tokbase);
    float4 acc = make_float4(0.f, 0.f, 0.f, 0.f);
#pragma unroll
    for (int t8 = 0; t8 < 32; t8 += 8) {
        const float4 wa = wp[t8 / 4];
        const float4 wb = wp[t8 / 4 + 1];
        float w[8];
        *(float4*)&w[0] = wa;
        *(float4*)&w[4] = wb;
#pragma unroll
        for (int j = 0; j < 8; ++j) {
            const float4 x = *(const float4*)(A + (tokbase + t8 + j) * 256 + dl);
            acc.x = fmaf(w[j], x.x, acc.x);
            acc.y = fmaf(w[j], x.y, acc.y);
            acc.z = fmaf(w[j], x.z, acc.z);
            acc.w = fmaf(w[j], x.w, acc.w);
        }
    }

    __shared__ float4 red[4][64];
    red[tg][l] = acc;
    __syncthreads();
    if (tg == 0) {
        float4 r = red[0][l];
        const float4 r1 = red[1][l], r2 = red[2][l], r3 = red[3][l];
        r.x += r1.x + r2.x + r3.x;
        r.y += r1.y + r2.y + r3.y;
        r.z += r1.z + r2.z + r3.z;
        r.w += r1.w + r2.w + r3.w;
        float* p = part + ((long)chunk * B + b) * D + dl;
        p[0] = r.x; p[1] = r.y; p[2] = r.z; p[3] = r.w;
    }
}

// ================= reduce partials -> context ================================
__global__ void context_reduce_kernel(const float* __restrict__ part,
                                      float* __restrict__ ctx) {
    const int i = blockIdx.x * 256 + threadIdx.x;
    float s = 0.f;
    for (int c = 0; c < NCH; ++c) s += part[(long)c * (B * D) + i];
    ctx[i] = s;
}

extern "C" void kernel_launch(void* const* d_in, const int* in_sizes, int n_in,
                              void* d_out, int out_size, void* d_ws, size_t ws_size,
                              hipStream_t stream) {
    const float* lstm = (const float*)d_in[0];  // [B,T,D]
    const float* W1   = (const float*)d_in[1];  // [D,U]
    const float* W2   = (const float*)d_in[2];  // [D,U]
    const float* v    = (const float*)d_in[3];  // [U,1]

    float* out  = (float*)d_out;
    float* ctx  = out;            // [B*D]
    float* attn = out + B * D;    // [B*T]

    float* part = (float*)d_ws;   // NCH*B*D floats = 2 MB

    scores_mfma_kernel<<<NBLK, 512, 0, stream>>>(lstm, W1, W2, v, attn);
    softmax_kernel<<<B, 1024, 0, stream>>>(attn);
    context_partial_kernel<<<dim3(NCH, B), 256, 0, stream>>>(lstm, attn, part);
    context_reduce_kernel<<<(B * D) / 256, 256, 0, stream>>>(part, ctx);
}